// Round 1
// baseline (1170.596 us; speedup 1.0000x reference)
//
#include <hip/hip_runtime.h>

// MultilayerGRU — key derivation (from the reference's faithful indexing bug):
//   states[0] is never updated -> layer 0's hidden input is ALWAYS the initial h0.
//   layer l>=1 reads states[l] right after layer l-1 wrote it THIS timestep.
//   => no time recurrence; every (b,t) is independent. The whole op is 7 GEMMs:
//   per layer: X@[Wz|Wr|Wg] (fused sigmoid / r*h / g-partial) then RH@Wgh (fused
//   tanh + update); finally H3@Wout. Layers 1,2 have x==h so Wzx+Wzh pre-summed.

typedef __attribute__((ext_vector_type(4))) float f32x4;
typedef __attribute__((ext_vector_type(8))) __bf16 bf16x8;

#define NROWS 65536          // B*S
#define HID_OFF 33554432ull  // B*S*O floats, start of hidden_out in d_out

__device__ __forceinline__ void gload16(const void* g, void* l) {
  __builtin_amdgcn_global_load_lds((const __attribute__((address_space(1))) void*)g,
                                   (__attribute__((address_space(3))) void*)l,
                                   16, 0, 0);
}

__device__ __forceinline__ float sigmoidf_(float x) {
  return 1.0f / (1.0f + __expf(-x));
}

// EPI: 0 = gates stage (N=1536: z|r|gpart), 1 = update stage (N=512), 2 = out GEMM
template<int EPI, bool L0>
__global__ __launch_bounds__(256, 2) void gemm_fused(
    const __bf16* __restrict__ A,    // chunk_rows x 512 bf16
    const __bf16* __restrict__ Bt,   // N x 512 bf16 (pre-transposed weights)
    int tiles_n, int row_off,
    const float* __restrict__ bias,  // gates: packed 1536; out: bout
    const float* __restrict__ cterm, // L0 gates: 64 x 1024 (h0@Wzh | h0@Wrh), fp32
    const float* __restrict__ h0f,   // L0: hidden_state base (B x 3*512)
    const __bf16* __restrict__ haux, // L>=1: h_in buffer (== A)
    const __bf16* __restrict__ gp_in,
    const __bf16* __restrict__ z_in,
    __bf16* __restrict__ o_z, __bf16* __restrict__ o_rh, __bf16* __restrict__ o_gp,
    __bf16* __restrict__ o_h, float* __restrict__ o_f)
{
  __shared__ alignas(16) __bf16 As[128 * 64];
  __shared__ alignas(16) __bf16 Bs[128 * 64];

  const int tid  = threadIdx.x;
  const int lane = tid & 63;
  const int w    = tid >> 6;
  const int tm   = blockIdx.x / tiles_n;
  const int tn   = blockIdx.x % tiles_n;
  const size_t arow0 = (size_t)tm * 128;
  const size_t brow0 = (size_t)tn * 128;

  const int wr = (w >> 1) * 64;
  const int wc = (w & 1) * 64;
  const int lrow = lane >> 3;          // 0..7
  const int lcol = (lane & 7) * 8;     // k element offset for staging

  f32x4 acc[4][4];
  const f32x4 zz = {0.f, 0.f, 0.f, 0.f};
  #pragma unroll
  for (int i = 0; i < 4; ++i)
    #pragma unroll
    for (int j = 0; j < 4; ++j) acc[i][j] = zz;

  for (int k0 = 0; k0 < 512; k0 += 64) {
    __syncthreads();
    #pragma unroll
    for (int p = 0; p < 4; ++p) {
      const int r = w * 8 + p * 32;  // wave-uniform LDS slab base
      gload16(A  + (arow0 + r + lrow) * 512 + k0 + lcol, &As[r * 64]);
      gload16(Bt + (brow0 + r + lrow) * 512 + k0 + lcol, &Bs[r * 64]);
    }
    __syncthreads();
    #pragma unroll
    for (int kk = 0; kk < 64; kk += 32) {
      bf16x8 af[4], bb[4];
      #pragma unroll
      for (int i = 0; i < 4; ++i) {
        af[i] = *(const bf16x8*)&As[(wr + i * 16 + (lane & 15)) * 64 + kk + (lane >> 4) * 8];
        bb[i] = *(const bf16x8*)&Bs[(wc + i * 16 + (lane & 15)) * 64 + kk + (lane >> 4) * 8];
      }
      #pragma unroll
      for (int mi = 0; mi < 4; ++mi)
        #pragma unroll
        for (int ni = 0; ni < 4; ++ni)
          acc[mi][ni] = __builtin_amdgcn_mfma_f32_16x16x32_bf16(af[mi], bb[ni], acc[mi][ni], 0, 0, 0);
    }
  }

  // epilogue — C/D layout (m89): col = lane&15, row = (lane>>4)*4 + reg
  const int fcol = lane & 15;
  const int frow = (lane >> 4) * 4;
  #pragma unroll
  for (int mi = 0; mi < 4; ++mi) {
    #pragma unroll
    for (int ni = 0; ni < 4; ++ni) {
      #pragma unroll
      for (int j = 0; j < 4; ++j) {
        const int rloc = (int)arow0 + wr + mi * 16 + frow + j;  // chunk-local row
        const int gcol = (int)brow0 + wc + ni * 16 + fcol;      // 0..N-1
        const int b    = (row_off + rloc) >> 10;                // global batch idx
        float c = acc[mi][ni][j];
        if (EPI == 0) {
          c += bias[gcol];
          if (gcol < 512) {                       // z gate
            if (L0) c += cterm[b * 1024 + gcol];
            o_z[(size_t)rloc * 512 + gcol] = (__bf16)sigmoidf_(c);
          } else if (gcol < 1024) {               // r gate -> r*h
            const int n = gcol - 512;
            if (L0) c += cterm[b * 1024 + gcol];
            const float rv = sigmoidf_(c);
            const float h = L0 ? h0f[b * 1536 + n] : (float)haux[(size_t)rloc * 512 + n];
            o_rh[(size_t)rloc * 512 + n] = (__bf16)(rv * h);
          } else {                                // g partial (x@Wgx + bgx)
            o_gp[(size_t)rloc * 512 + (gcol - 1024)] = (__bf16)c;
          }
        } else if (EPI == 1) {
          const float gv = tanhf((float)gp_in[(size_t)rloc * 512 + gcol] + c);
          const float zv = (float)z_in[(size_t)rloc * 512 + gcol];
          const float h  = L0 ? h0f[b * 1536 + gcol] : (float)haux[(size_t)rloc * 512 + gcol];
          o_h[(size_t)rloc * 512 + gcol] = (__bf16)(zv * h + (1.f - zv) * gv);
        } else {
          o_f[(size_t)rloc * 512 + gcol] = c + bias[gcol];
        }
      }
    }
  }
}

// Transpose+pack 13 weight matrices (fp32 -> bf16, with pre-sum for layers 1,2 z/r).
// slot 0..8: layer l=s/3, gate g=s%3 -> W1t[l] rows [g*512..g*512+512) = (Wx + Wh?)^T
// slot 9..11: Wgh[l]^T ; slot 12: Wout^T
__global__ void prep_pack(const float* __restrict__ Wzx, const float* __restrict__ Wzh,
                          const float* __restrict__ Wrx, const float* __restrict__ Wrh,
                          const float* __restrict__ Wgx, const float* __restrict__ Wgh,
                          const float* __restrict__ Wout,
                          __bf16* __restrict__ W1t, __bf16* __restrict__ Wght,
                          __bf16* __restrict__ Woutt)
{
  const int slot = blockIdx.z;
  const float* srcA;
  const float* srcB = nullptr;
  __bf16* dst;
  if (slot < 9) {
    const int l = slot / 3, g = slot % 3;
    srcA = (g == 0 ? Wzx : g == 1 ? Wrx : Wgx) + (size_t)l * 512 * 512;
    if (l > 0 && g < 2) srcB = (g == 0 ? Wzh : Wrh) + (size_t)l * 512 * 512;
    dst = W1t + (size_t)l * 1536 * 512 + (size_t)g * 512 * 512;
  } else if (slot < 12) {
    const int l = slot - 9;
    srcA = Wgh + (size_t)l * 512 * 512;
    dst = Wght + (size_t)l * 512 * 512;
  } else {
    srcA = Wout;
    dst = Woutt;
  }
  __shared__ float tile[32][33];
  const int k0 = blockIdx.x * 32;
  const int n0 = blockIdx.y * 32;
  const int tx = threadIdx.x;   // 0..31
  const int ty = threadIdx.y;   // 0..7
  for (int i = ty; i < 32; i += 8) {
    float v = srcA[(size_t)(k0 + i) * 512 + n0 + tx];
    if (srcB) v += srcB[(size_t)(k0 + i) * 512 + n0 + tx];
    tile[i][tx] = v;
  }
  __syncthreads();
  for (int i = ty; i < 32; i += 8)
    dst[(size_t)(n0 + i) * 512 + k0 + tx] = (__bf16)tile[tx][i];
}

// Cterm[b][0..511] = h0[b]@Wzh[0], [512..1023] = h0[b]@Wrh[0]  (exact fp32)
__global__ void cterm_kernel(const float* __restrict__ hidden,
                             const float* __restrict__ Wzh,
                             const float* __restrict__ Wrh,
                             float* __restrict__ Cterm)
{
  const int idx = blockIdx.x * blockDim.x + threadIdx.x;  // 0..65535
  const int b = idx >> 10;
  const int n = idx & 1023;
  const float* W = (n < 512 ? Wzh : Wrh);
  const int nn = n & 511;
  const float* h0 = hidden + (size_t)b * 1536;  // (B,3,512) l=0 slice
  float acc = 0.f;
  for (int k = 0; k < 512; ++k) acc += h0[k] * W[(size_t)k * 512 + nn];
  Cterm[idx] = acc;
}

// Pack biases [bzx|brx|bgx] per layer, and copy hidden_out[:,0,:] = h0 (exact).
__global__ void small_prep(const float* __restrict__ bzx, const float* __restrict__ brx,
                           const float* __restrict__ bgx, const float* __restrict__ hidden,
                           float* __restrict__ bias1, float* __restrict__ out_hidden)
{
  const int idx = blockIdx.x * blockDim.x + threadIdx.x;
  if (idx < 3 * 1536) {
    const int l = idx / 1536, j = idx % 1536;
    const float* src = (j < 512 ? bzx : j < 1024 ? brx : bgx);
    bias1[idx] = src[l * 512 + (j & 511)];
  }
  const int hidx = idx - 3 * 1536;
  if (hidx >= 0 && hidx < 64 * 512) {
    const int b = hidx >> 9, n = hidx & 511;
    out_hidden[(size_t)b * 1536 + n] = hidden[(size_t)b * 1536 + n];
  }
}

__global__ void convert_x(const float* __restrict__ src, __bf16* __restrict__ dst, long n)
{
  const long i = ((long)blockIdx.x * blockDim.x + threadIdx.x) * 8;
  if (i >= n) return;
  const f32x4 a = *(const f32x4*)(src + i);
  const f32x4 b = *(const f32x4*)(src + i + 4);
  bf16x8 o;
  o[0] = (__bf16)a[0]; o[1] = (__bf16)a[1]; o[2] = (__bf16)a[2]; o[3] = (__bf16)a[3];
  o[4] = (__bf16)b[0]; o[5] = (__bf16)b[1]; o[6] = (__bf16)b[2]; o[7] = (__bf16)b[3];
  *(bf16x8*)(dst + i) = o;
}

// Pull t=S-1 rows of a chunk's h buffer into hidden_out slot (dst already +l*512).
__global__ void extract_h(const __bf16* __restrict__ hbuf, float* __restrict__ dst,
                          int b0, int total)
{
  const int idx = blockIdx.x * blockDim.x + threadIdx.x;
  if (idx >= total) return;
  const int bi = idx >> 9;
  const int n  = idx & 511;
  dst[(size_t)(b0 + bi) * 1536 + n] = (float)hbuf[((size_t)bi * 1024 + 1023) * 512 + n];
}

extern "C" void kernel_launch(void* const* d_in, const int* in_sizes, int n_in,
                              void* d_out, int out_size, void* d_ws, size_t ws_size,
                              hipStream_t stream) {
  const float* input  = (const float*)d_in[0];
  const float* hidden = (const float*)d_in[1];
  const float* Wzx = (const float*)d_in[2];
  const float* bzx = (const float*)d_in[3];
  const float* Wzh = (const float*)d_in[4];
  const float* Wrx = (const float*)d_in[5];
  const float* brx = (const float*)d_in[6];
  const float* Wrh = (const float*)d_in[7];
  const float* Wgx = (const float*)d_in[8];
  const float* bgx = (const float*)d_in[9];
  const float* Wgh = (const float*)d_in[10];
  const float* Wout = (const float*)d_in[11];
  const float* bout = (const float*)d_in[12];

  float* out = (float*)d_out;
  float* out_hidden = out + HID_OFF;

  char* ws = (char*)d_ws;
  size_t off = 0;
  auto carve = [&](size_t bytes) -> void* {
    off = (off + 255) & ~(size_t)255;
    void* p = ws + off;
    off += bytes;
    return p;
  };

  __bf16* W1t   = (__bf16*)carve(3ull * 1536 * 512 * 2);
  __bf16* Wght  = (__bf16*)carve(3ull * 512 * 512 * 2);
  __bf16* Woutt = (__bf16*)carve(512ull * 512 * 2);
  float*  bias1 = (float*) carve(3ull * 1536 * 4);
  float*  Cterm = (float*) carve(64ull * 1024 * 4);
  const size_t fixed_end = off;

  // pick largest chunk (fewest chunks) that fits ws
  long chunk_rows = NROWS;
  int C = 1;
  while (C < 64) {
    const size_t need = ((fixed_end + 255) & ~(size_t)255) +
                        5ull * (size_t)chunk_rows * 512 * 2 + 5 * 256;
    if (need <= ws_size) break;
    C *= 2;
    chunk_rows /= 2;
  }
  __bf16* bufA = (__bf16*)carve((size_t)chunk_rows * 512 * 2);
  __bf16* bufB = (__bf16*)carve((size_t)chunk_rows * 512 * 2);
  __bf16* zb   = (__bf16*)carve((size_t)chunk_rows * 512 * 2);
  __bf16* rhb  = (__bf16*)carve((size_t)chunk_rows * 512 * 2);
  __bf16* gpb  = (__bf16*)carve((size_t)chunk_rows * 512 * 2);

  // one-time prep
  small_prep<<<(3 * 1536 + 64 * 512 + 255) / 256, 256, 0, stream>>>(
      bzx, brx, bgx, hidden, bias1, out_hidden);
  dim3 tp_grid(16, 16, 13), tp_blk(32, 8);
  prep_pack<<<tp_grid, tp_blk, 0, stream>>>(Wzx, Wzh, Wrx, Wrh, Wgx, Wgh, Wout,
                                            W1t, Wght, Woutt);
  cterm_kernel<<<65536 / 256, 256, 0, stream>>>(hidden, Wzh, Wrh, Cterm);

  for (int c = 0; c < C; ++c) {
    const long row_off = (long)c * chunk_rows;
    const long nelem = chunk_rows * 512;
    const int  mt = (int)(chunk_rows / 128);
    const int  ext_total = (int)(chunk_rows / 1024) * 512;
    const int  b0 = (int)(row_off >> 10);

    convert_x<<<(int)((nelem / 8 + 255) / 256), 256, 0, stream>>>(
        input + (size_t)row_off * 512, bufA, nelem);

    // layer 0
    gemm_fused<0, true><<<mt * 12, 256, 0, stream>>>(
        bufA, W1t, 12, (int)row_off, bias1, Cterm, hidden, nullptr, nullptr, nullptr,
        zb, rhb, gpb, nullptr, nullptr);
    gemm_fused<1, true><<<mt * 4, 256, 0, stream>>>(
        rhb, Wght, 4, (int)row_off, nullptr, nullptr, hidden, nullptr, gpb, zb,
        nullptr, nullptr, nullptr, bufB, nullptr);
    extract_h<<<(ext_total + 255) / 256, 256, 0, stream>>>(bufB, out_hidden + 512, b0, ext_total);

    // layer 1 (x == h == bufB)
    gemm_fused<0, false><<<mt * 12, 256, 0, stream>>>(
        bufB, W1t + 1536 * 512, 12, (int)row_off, bias1 + 1536, nullptr, nullptr, bufB,
        nullptr, nullptr, zb, rhb, gpb, nullptr, nullptr);
    gemm_fused<1, false><<<mt * 4, 256, 0, stream>>>(
        rhb, Wght + 512 * 512, 4, (int)row_off, nullptr, nullptr, nullptr, bufB, gpb, zb,
        nullptr, nullptr, nullptr, bufA, nullptr);
    extract_h<<<(ext_total + 255) / 256, 256, 0, stream>>>(bufA, out_hidden + 1024, b0, ext_total);

    // layer 2 (x == h == bufA)
    gemm_fused<0, false><<<mt * 12, 256, 0, stream>>>(
        bufA, W1t + 2 * 1536 * 512, 12, (int)row_off, bias1 + 3072, nullptr, nullptr, bufA,
        nullptr, nullptr, zb, rhb, gpb, nullptr, nullptr);
    gemm_fused<1, false><<<mt * 4, 256, 0, stream>>>(
        rhb, Wght + 2 * 512 * 512, 4, (int)row_off, nullptr, nullptr, nullptr, bufA, gpb, zb,
        nullptr, nullptr, nullptr, bufB, nullptr);

    // output projection
    gemm_fused<2, false><<<mt * 4, 256, 0, stream>>>(
        bufB, Woutt, 4, (int)row_off, bout, nullptr, nullptr, nullptr, nullptr, nullptr,
        nullptr, nullptr, nullptr, nullptr, out + (size_t)row_off * 512);
  }
}

// Round 2
// 1100.041 us; speedup vs baseline: 1.0641x; 1.0641x over previous
//
#include <hip/hip_runtime.h>

// MultilayerGRU — reference's faithful indexing bug makes every (b,t) independent:
// 7 chained GEMMs over a 65536x512 activation matrix. This round: 256x256 BK=64
// 8-wave 8-phase GEMM (T1 XCD swizzle + T2 LDS XOR swizzle + T3/T4 counted vmcnt
// + T5 setprio), fused gate epilogues.

typedef __attribute__((ext_vector_type(4))) float f32x4;
typedef __attribute__((ext_vector_type(8))) __bf16 bf16x8;

#define NROWS 65536          // B*S
#define HID_OFF 33554432ull  // B*S*O floats, start of hidden_out in d_out

__device__ __forceinline__ void gload16(const void* g, void* l) {
  __builtin_amdgcn_global_load_lds((const __attribute__((address_space(1))) void*)g,
                                   (__attribute__((address_space(3))) void*)l,
                                   16, 0, 0);
}
__device__ __forceinline__ void wgbar() { asm volatile("s_barrier" ::: "memory"); }
__device__ __forceinline__ float sigmoidf_(float x) { return 1.f / (1.f + __expf(-x)); }
__device__ __forceinline__ float tanh_fast(float x) {
  const float e = __expf(2.f * x);
  return 1.f - 2.f / (e + 1.f);   // monotone-safe at +-inf
}

// Stage one 128x64 bf16 half-tile: LDS dest linear (gload_lds requirement),
// global source pre-permuted with the involution cc ^= row&7 on 16B chunks
// (rule 21: inverse-swz SOURCE + swz READ).
__device__ __forceinline__ void stage_half(const __bf16* __restrict__ src,
                                           __bf16* lds, int w, int lane) {
#pragma unroll
  for (int i = 0; i < 2; ++i) {
    const int s0 = (w * 2 + i) * 64;      // wave-uniform chunk base
    const int s = s0 + lane;              // 16B chunk index 0..1023
    const int row = s >> 3;               // 0..127
    const int cc = (s & 7) ^ (row & 7);   // which global chunk lands here
    gload16(src + (size_t)row * 512 + cc * 8, lds + s0 * 8);
  }
}

// Swizzled fragment read: row-major 256x64 tile, chunk cc XOR row&7.
__device__ __forceinline__ bf16x8 frag_ld(const __bf16* tile, int row, int ks, int lane) {
  const int cc = (ks * 4 + (lane >> 4)) ^ (row & 7);
  return *(const bf16x8*)(tile + row * 64 + cc * 8);
}

// EPI: 0 = gates (N=1536: z|r|gpart), 1 = update (N=512), 2 = out GEMM (N=512)
template<int EPI, bool L0>
__global__ __launch_bounds__(512, 2) void gemm_fused(
    const __bf16* __restrict__ A,    // chunk_rows x 512
    const __bf16* __restrict__ Bt,   // N x 512 (pre-transposed weights)
    int tiles_n, int row_off,
    const float* __restrict__ bias,
    const float* __restrict__ cterm,  // L0 gates: 64 x 1024 fp32
    const float* __restrict__ h0f,    // L0: hidden_state base (B x 3*512)
    const __bf16* __restrict__ haux,  // L>=1: h_in buffer (== A)
    const __bf16* __restrict__ gp_in,
    const __bf16* __restrict__ z_in,
    __bf16* __restrict__ o_z, __bf16* __restrict__ o_rh, __bf16* __restrict__ o_gp,
    __bf16* __restrict__ o_h, float* __restrict__ o_f)
{
  __shared__ __bf16 smem[4 * 256 * 64];   // 128 KiB: [buf][A|B][256][64]
  __bf16* const As0 = smem;
  __bf16* const Bs0 = smem + 256 * 64;
  __bf16* const As1 = smem + 2 * 256 * 64;
  __bf16* const Bs1 = smem + 3 * 256 * 64;
  __bf16* const Asb[2] = { As0, As1 };
  __bf16* const Bsb[2] = { Bs0, Bs1 };

  const int tid = threadIdx.x, lane = tid & 63, w = tid >> 6;
  const int wm = w >> 2, wn = w & 3;

  // T1: bijective XCD swizzle (m204) — 6 n-tiles of one A-panel share an XCD L2
  int bid = blockIdx.x;
  {
    const int nwg = gridDim.x;
    const int q = nwg >> 3, r = nwg & 7;
    const int x = bid & 7, rest = bid >> 3;
    bid = (x < r ? x * (q + 1) : r * (q + 1) + (x - r) * q) + rest;
  }
  const int tm = bid / tiles_n, tn = bid - tm * tiles_n;

  const size_t arow0 = (size_t)tm * 256;
  const int brow0 = tn * 256;
  const __bf16* const Ab = A + arow0 * 512;
  const __bf16* const Bb = Bt + (size_t)brow0 * 512;

  f32x4 acc[8][4];
  const f32x4 zz = {0.f, 0.f, 0.f, 0.f};
#pragma unroll
  for (int i = 0; i < 8; ++i)
#pragma unroll
    for (int j = 0; j < 4; ++j) acc[i][j] = zz;

  bf16x8 a[4][2], b0[2][2], b1[2][2];

  auto read_A = [&](const __bf16* T, int mh) {
#pragma unroll
    for (int mi = 0; mi < 4; ++mi)
#pragma unroll
      for (int ks = 0; ks < 2; ++ks)
        a[mi][ks] = frag_ld(T, wm * 128 + mh * 64 + mi * 16 + (lane & 15), ks, lane);
  };
  auto read_B = [&](const __bf16* T, int nhh, bf16x8 (&b)[2][2]) {
#pragma unroll
    for (int ni = 0; ni < 2; ++ni)
#pragma unroll
      for (int ks = 0; ks < 2; ++ks)
        b[ni][ks] = frag_ld(T, wn * 64 + nhh * 32 + ni * 16 + (lane & 15), ks, lane);
  };
  auto mfma_q = [&](int mh, int nhh, bf16x8 (&b)[2][2]) {
    __builtin_amdgcn_s_setprio(1);
#pragma unroll
    for (int mi = 0; mi < 4; ++mi)
#pragma unroll
      for (int ni = 0; ni < 2; ++ni)
#pragma unroll
        for (int ks = 0; ks < 2; ++ks)
          acc[mh * 4 + mi][nhh * 2 + ni] = __builtin_amdgcn_mfma_f32_16x16x32_bf16(
              a[mi][ks], b[ni][ks], acc[mh * 4 + mi][nhh * 2 + ni], 0, 0, 0);
    __builtin_amdgcn_s_setprio(0);
  };

  constexpr int NT = 8;  // K=512 / BK=64
  // prologue: tile0 fully + B(1); A(1) arrives in ph1-2 of t=0, B(2) in ph3-4.
  stage_half(Bb, Bs0, w, lane);
  stage_half(Bb + 128 * 512, Bs0 + 128 * 64, w, lane);
  stage_half(Ab, As0, w, lane);
  stage_half(Ab + 128 * 512, As0 + 128 * 64, w, lane);
  stage_half(Bb + 64, Bs1, w, lane);
  stage_half(Bb + 128 * 512 + 64, Bs1 + 128 * 64, w, lane);
  asm volatile("s_waitcnt vmcnt(4)" ::: "memory");  // tile0 landed; B(1) in flight
  wgbar();

#pragma unroll
  for (int t = 0; t < NT; ++t) {
    const __bf16* const At_ = Asb[t & 1];
    const __bf16* const Bt_ = Bsb[t & 1];
    // ---- phase 1: quadrant (mh0, nh0)
    read_A(At_, 0);
    read_B(Bt_, 0, b0);
    if (t + 1 < NT) stage_half(Ab + (t + 1) * 64, Asb[(t + 1) & 1], w, lane);
    wgbar();
    mfma_q(0, 0, b0);
    wgbar();
    // ---- phase 2: (mh0, nh1)
    read_B(Bt_, 1, b1);
    if (t + 1 < NT) stage_half(Ab + 128 * 512 + (t + 1) * 64,
                               Asb[(t + 1) & 1] + 128 * 64, w, lane);
    wgbar();
    mfma_q(0, 1, b1);
    wgbar();
    // ---- phase 3: (mh1, nh1)  — B region of this buffer fully read by end ph2
    read_A(At_, 1);
    if (t + 2 < NT) stage_half(Bb + (t + 2) * 64, Bsb[t & 1], w, lane);
    wgbar();
    mfma_q(1, 1, b1);
    wgbar();
    // ---- phase 4: (mh1, nh0)  — A region fully read by end ph3
    if (t + 2 < NT) stage_half(Bb + 128 * 512 + (t + 2) * 64,
                               Bsb[t & 1] + 128 * 64, w, lane);
    wgbar();
    mfma_q(1, 0, b0);
    if (t + 1 < NT) {  // counted wait: tile t+1 complete; B(t+2) (4 loads) stays in flight
      if (t + 2 < NT) asm volatile("s_waitcnt vmcnt(4)" ::: "memory");
      else            asm volatile("s_waitcnt vmcnt(0)" ::: "memory");
    }
    wgbar();
  }

  // epilogue — C/D layout (m89): col = lane&15, row = (lane>>4)*4 + reg
  const int fcol = lane & 15;
  const int frow = (lane >> 4) * 4;
#pragma unroll
  for (int m = 0; m < 8; ++m) {
#pragma unroll
    for (int n = 0; n < 4; ++n) {
#pragma unroll
      for (int j = 0; j < 4; ++j) {
        const int rloc = (int)arow0 + wm * 128 + m * 16 + frow + j;
        const int gcol = brow0 + wn * 64 + n * 16 + fcol;
        const int b = (row_off + rloc) >> 10;
        float c = acc[m][n][j];
        if (EPI == 0) {
          c += bias[gcol];
          if (gcol < 512) {                       // z gate
            if (L0) c += cterm[b * 1024 + gcol];
            o_z[(size_t)rloc * 512 + gcol] = (__bf16)sigmoidf_(c);
          } else if (gcol < 1024) {               // r gate -> r*h
            const int nn = gcol - 512;
            if (L0) c += cterm[b * 1024 + gcol];
            const float rv = sigmoidf_(c);
            const float h = L0 ? h0f[b * 1536 + nn] : (float)haux[(size_t)rloc * 512 + nn];
            o_rh[(size_t)rloc * 512 + nn] = (__bf16)(rv * h);
          } else {                                // g partial (x@Wgx + bgx)
            o_gp[(size_t)rloc * 512 + (gcol - 1024)] = (__bf16)c;
          }
        } else if (EPI == 1) {
          const float gv = tanh_fast((float)gp_in[(size_t)rloc * 512 + gcol] + c);
          const float zv = (float)z_in[(size_t)rloc * 512 + gcol];
          const float h = L0 ? h0f[b * 1536 + gcol] : (float)haux[(size_t)rloc * 512 + gcol];
          o_h[(size_t)rloc * 512 + gcol] = (__bf16)(zv * h + (1.f - zv) * gv);
        } else {
          o_f[(size_t)rloc * 512 + gcol] = c + bias[gcol];
        }
      }
    }
  }
}

// ---- prep kernels (unchanged from passing round-1 version) ----

__global__ void prep_pack(const float* __restrict__ Wzx, const float* __restrict__ Wzh,
                          const float* __restrict__ Wrx, const float* __restrict__ Wrh,
                          const float* __restrict__ Wgx, const float* __restrict__ Wgh,
                          const float* __restrict__ Wout,
                          __bf16* __restrict__ W1t, __bf16* __restrict__ Wght,
                          __bf16* __restrict__ Woutt)
{
  const int slot = blockIdx.z;
  const float* srcA;
  const float* srcB = nullptr;
  __bf16* dst;
  if (slot < 9) {
    const int l = slot / 3, g = slot % 3;
    srcA = (g == 0 ? Wzx : g == 1 ? Wrx : Wgx) + (size_t)l * 512 * 512;
    if (l > 0 && g < 2) srcB = (g == 0 ? Wzh : Wrh) + (size_t)l * 512 * 512;
    dst = W1t + (size_t)l * 1536 * 512 + (size_t)g * 512 * 512;
  } else if (slot < 12) {
    const int l = slot - 9;
    srcA = Wgh + (size_t)l * 512 * 512;
    dst = Wght + (size_t)l * 512 * 512;
  } else {
    srcA = Wout;
    dst = Woutt;
  }
  __shared__ float tile[32][33];
  const int k0 = blockIdx.x * 32;
  const int n0 = blockIdx.y * 32;
  const int tx = threadIdx.x;
  const int ty = threadIdx.y;
  for (int i = ty; i < 32; i += 8) {
    float v = srcA[(size_t)(k0 + i) * 512 + n0 + tx];
    if (srcB) v += srcB[(size_t)(k0 + i) * 512 + n0 + tx];
    tile[i][tx] = v;
  }
  __syncthreads();
  for (int i = ty; i < 32; i += 8)
    dst[(size_t)(n0 + i) * 512 + k0 + tx] = (__bf16)tile[tx][i];
}

__global__ void cterm_kernel(const float* __restrict__ hidden,
                             const float* __restrict__ Wzh,
                             const float* __restrict__ Wrh,
                             float* __restrict__ Cterm)
{
  const int idx = blockIdx.x * blockDim.x + threadIdx.x;
  const int b = idx >> 10;
  const int n = idx & 1023;
  const float* W = (n < 512 ? Wzh : Wrh);
  const int nn = n & 511;
  const float* h0 = hidden + (size_t)b * 1536;
  float acc = 0.f;
  for (int k = 0; k < 512; ++k) acc += h0[k] * W[(size_t)k * 512 + nn];
  Cterm[idx] = acc;
}

__global__ void small_prep(const float* __restrict__ bzx, const float* __restrict__ brx,
                           const float* __restrict__ bgx, const float* __restrict__ hidden,
                           float* __restrict__ bias1, float* __restrict__ out_hidden)
{
  const int idx = blockIdx.x * blockDim.x + threadIdx.x;
  if (idx < 3 * 1536) {
    const int l = idx / 1536, j = idx % 1536;
    const float* src = (j < 512 ? bzx : j < 1024 ? brx : bgx);
    bias1[idx] = src[l * 512 + (j & 511)];
  }
  const int hidx = idx - 3 * 1536;
  if (hidx >= 0 && hidx < 64 * 512) {
    const int b = hidx >> 9, n = hidx & 511;
    out_hidden[(size_t)b * 1536 + n] = hidden[(size_t)b * 1536 + n];
  }
}

__global__ void convert_x(const float* __restrict__ src, __bf16* __restrict__ dst, long n)
{
  const long i = ((long)blockIdx.x * blockDim.x + threadIdx.x) * 8;
  if (i >= n) return;
  const f32x4 a = *(const f32x4*)(src + i);
  const f32x4 b = *(const f32x4*)(src + i + 4);
  bf16x8 o;
  o[0] = (__bf16)a[0]; o[1] = (__bf16)a[1]; o[2] = (__bf16)a[2]; o[3] = (__bf16)a[3];
  o[4] = (__bf16)b[0]; o[5] = (__bf16)b[1]; o[6] = (__bf16)b[2]; o[7] = (__bf16)b[3];
  *(bf16x8*)(dst + i) = o;
}

__global__ void extract_h(const __bf16* __restrict__ hbuf, float* __restrict__ dst,
                          int b0, int total)
{
  const int idx = blockIdx.x * blockDim.x + threadIdx.x;
  if (idx >= total) return;
  const int bi = idx >> 9;
  const int n = idx & 511;
  dst[(size_t)(b0 + bi) * 1536 + n] = (float)hbuf[((size_t)bi * 1024 + 1023) * 512 + n];
}

extern "C" void kernel_launch(void* const* d_in, const int* in_sizes, int n_in,
                              void* d_out, int out_size, void* d_ws, size_t ws_size,
                              hipStream_t stream) {
  const float* input  = (const float*)d_in[0];
  const float* hidden = (const float*)d_in[1];
  const float* Wzx = (const float*)d_in[2];
  const float* bzx = (const float*)d_in[3];
  const float* Wzh = (const float*)d_in[4];
  const float* Wrx = (const float*)d_in[5];
  const float* brx = (const float*)d_in[6];
  const float* Wrh = (const float*)d_in[7];
  const float* Wgx = (const float*)d_in[8];
  const float* bgx = (const float*)d_in[9];
  const float* Wgh = (const float*)d_in[10];
  const float* Wout = (const float*)d_in[11];
  const float* bout = (const float*)d_in[12];

  float* out = (float*)d_out;
  float* out_hidden = out + HID_OFF;

  char* ws = (char*)d_ws;
  size_t off = 0;
  auto carve = [&](size_t bytes) -> void* {
    off = (off + 255) & ~(size_t)255;
    void* p = ws + off;
    off += bytes;
    return p;
  };

  __bf16* W1t   = (__bf16*)carve(3ull * 1536 * 512 * 2);
  __bf16* Wght  = (__bf16*)carve(3ull * 512 * 512 * 2);
  __bf16* Woutt = (__bf16*)carve(512ull * 512 * 2);
  float*  bias1 = (float*) carve(3ull * 1536 * 4);
  float*  Cterm = (float*) carve(64ull * 1024 * 4);
  const size_t fixed_end = off;

  long chunk_rows = NROWS;
  int C = 1;
  while (C < 32) {
    const size_t need = ((fixed_end + 255) & ~(size_t)255) +
                        5ull * (size_t)chunk_rows * 512 * 2 + 5 * 256;
    if (need <= ws_size) break;
    C *= 2;
    chunk_rows /= 2;
  }
  __bf16* bufA = (__bf16*)carve((size_t)chunk_rows * 512 * 2);
  __bf16* bufB = (__bf16*)carve((size_t)chunk_rows * 512 * 2);
  __bf16* zb   = (__bf16*)carve((size_t)chunk_rows * 512 * 2);
  __bf16* rhb  = (__bf16*)carve((size_t)chunk_rows * 512 * 2);
  __bf16* gpb  = (__bf16*)carve((size_t)chunk_rows * 512 * 2);

  small_prep<<<(3 * 1536 + 64 * 512 + 255) / 256, 256, 0, stream>>>(
      bzx, brx, bgx, hidden, bias1, out_hidden);
  dim3 tp_grid(16, 16, 13), tp_blk(32, 8);
  prep_pack<<<tp_grid, tp_blk, 0, stream>>>(Wzx, Wzh, Wrx, Wrh, Wgx, Wgh, Wout,
                                            W1t, Wght, Woutt);
  cterm_kernel<<<65536 / 256, 256, 0, stream>>>(hidden, Wzh, Wrh, Cterm);

  for (int c = 0; c < C; ++c) {
    const long row_off = (long)c * chunk_rows;
    const long nelem = chunk_rows * 512;
    const int mt = (int)(chunk_rows / 256);
    const int ext_total = (int)(chunk_rows / 1024) * 512;
    const int b0 = (int)(row_off >> 10);

    convert_x<<<(int)((nelem / 8 + 255) / 256), 256, 0, stream>>>(
        input + (size_t)row_off * 512, bufA, nelem);

    // layer 0
    gemm_fused<0, true><<<mt * 6, 512, 0, stream>>>(
        bufA, W1t, 6, (int)row_off, bias1, Cterm, hidden, nullptr, nullptr, nullptr,
        zb, rhb, gpb, nullptr, nullptr);
    gemm_fused<1, true><<<mt * 2, 512, 0, stream>>>(
        rhb, Wght, 2, (int)row_off, nullptr, nullptr, hidden, nullptr, gpb, zb,
        nullptr, nullptr, nullptr, bufB, nullptr);
    extract_h<<<(ext_total + 255) / 256, 256, 0, stream>>>(bufB, out_hidden + 512, b0, ext_total);

    // layer 1 (x == h == bufB)
    gemm_fused<0, false><<<mt * 6, 512, 0, stream>>>(
        bufB, W1t + 1536 * 512, 6, (int)row_off, bias1 + 1536, nullptr, nullptr, bufB,
        nullptr, nullptr, zb, rhb, gpb, nullptr, nullptr);
    gemm_fused<1, false><<<mt * 2, 512, 0, stream>>>(
        rhb, Wght + 512 * 512, 2, (int)row_off, nullptr, nullptr, nullptr, bufB, gpb, zb,
        nullptr, nullptr, nullptr, bufA, nullptr);
    extract_h<<<(ext_total + 255) / 256, 256, 0, stream>>>(bufA, out_hidden + 1024, b0, ext_total);

    // layer 2 (x == h == bufA)
    gemm_fused<0, false><<<mt * 6, 512, 0, stream>>>(
        bufA, W1t + 2 * 1536 * 512, 6, (int)row_off, bias1 + 3072, nullptr, nullptr, bufA,
        nullptr, nullptr, zb, rhb, gpb, nullptr, nullptr);
    gemm_fused<1, false><<<mt * 2, 512, 0, stream>>>(
        rhb, Wght + 2 * 512 * 512, 2, (int)row_off, nullptr, nullptr, nullptr, bufA, gpb, zb,
        nullptr, nullptr, nullptr, bufB, nullptr);

    // output projection
    gemm_fused<2, false><<<mt * 2, 512, 0, stream>>>(
        bufB, Woutt, 2, (int)row_off, bout, nullptr, nullptr, nullptr, nullptr, nullptr,
        nullptr, nullptr, nullptr, nullptr, out + (size_t)row_off * 512);
  }
}